// Round 6
// baseline (1786.666 us; speedup 1.0000x reference)
//
#include <hip/hip_runtime.h>
#include <hip/hip_bf16.h>

#define N_NODES 50000
#define VOCAB   2048
#define HID     256
#define N_EDGES 1600000

typedef __attribute__((ext_vector_type(8))) __bf16 bf16x8;
typedef __attribute__((ext_vector_type(4))) __bf16 bf16x4;
typedef __attribute__((ext_vector_type(4))) float  f32x4;

__device__ __forceinline__ float bf2f(unsigned short u) {
    return __uint_as_float(((unsigned)u) << 16);
}

// ---------------------------------------------------------------------------
// one-time fp32 -> bf16 weight preconvert (2 MB total)
// ---------------------------------------------------------------------------
__global__ __launch_bounds__(256) void cvt_f32_bf16(
    const float* __restrict__ in, __bf16* __restrict__ out, int n4)
{
    const int t = blockIdx.x * 256 + threadIdx.x;
    if (t < n4) {
        const float4 v = ((const float4*)in)[t];
        bf16x4 p = { (__bf16)v.x, (__bf16)v.y, (__bf16)v.z, (__bf16)v.w };
        ((bf16x4*)out)[t] = p;
    }
}

// ---------------------------------------------------------------------------
// Pipelined GEMM, B^T: C[M][N] = A[M][K]*B[N][K]^T (+bias)
// BM=128, BN=256, BK=32, 8 waves (2x4) of 64x64, 4x4 frags 16x16x32.
// Depth-2 register prefetch for BOTH A and B; raw s_barrier + lgkmcnt(0)
// only (no vmcnt drain in the loop -> t+2 loads stay in flight, T4-style).
// LDK=36: 72B row stride == 18 dwords, gcd(18,32)=2 -> 2-way max (free).
// B tile = 256 rows x 32 bf16 = 1024 uint4 -> 2 uint4 per thread (the
// round-5 bug: only 1 was staged, half of sB was poison).
// ---------------------------------------------------------------------------
template<bool A_F32, bool OUT_BF16, bool BIAS>
__global__ __launch_bounds__(512, 4) void gemm_p2(
    const void*   __restrict__ Araw,  // [M][K] fp32 or bf16
    const __bf16* __restrict__ Bb,    // [N][K] bf16
    const float*  __restrict__ bias,  // [N] or nullptr
    void*         __restrict__ Craw,  // [M][N] bf16 or fp32
    int M, int N, int K, int nby)
{
    constexpr int BM = 128, BN = 256, BK = 32, LDK = 36;
    __shared__ __bf16 sA[2][BM * LDK];   // 2 x  9216 B
    __shared__ __bf16 sB[2][BN * LDK];   // 2 x 18432 B  (55296 B total)

    const int tid  = threadIdx.x;
    const int lane = tid & 63;
    const int wid  = tid >> 6;        // 0..7
    const int wm   = wid >> 2;        // 0..1
    const int wn   = wid & 3;         // 0..3
    const int half = lane >> 4;       // 0..3
    const int r16  = lane & 15;

    // XCD-bijective swizzle (m204)
    int wg = blockIdx.x;
    {
        const int nwg = gridDim.x;
        const int q = nwg >> 3, r = nwg & 7;
        const int x = wg & 7, o = wg >> 3;
        wg = (x < r ? x * (q + 1) : r * (q + 1) + (x - r) * q) + o;
    }
    const int m0 = (wg / nby) * BM;
    const int n0 = (wg % nby) * BN;

    const float*  Af = (const float*)Araw;
    const __bf16* Ab = (const __bf16*)Araw;

    f32x4 acc[4][4] = {};
    float4 qf0[2], qf1[2];   // A queues (fp32 path)
    uint4  qb0, qb1;         // A queues (bf16 path)
    uint4  qB0[2], qB1[2];   // B queues
    const int nkt = K / BK;

    auto loadA = [&](int kt, float4 (&qf)[2], uint4& qb) {
        const int k0 = kt * BK;
        if constexpr (A_F32) {
            #pragma unroll
            for (int i = 0; i < 2; ++i) {
                const int s = i * 512 + tid;          // 0..1023
                const int row = s >> 3, cg = s & 7;   // 128 rows x 8 float4
                const int gr = m0 + row;
                qf[i] = (gr < M) ? *(const float4*)&Af[(size_t)gr * K + k0 + cg * 4]
                                 : make_float4(0.f, 0.f, 0.f, 0.f);
            }
        } else {
            const int row = tid >> 2, cg = tid & 3;   // 128 rows x 4 bf16x8
            const int gr = m0 + row;
            qb = (gr < M) ? *(const uint4*)&Ab[(size_t)gr * K + k0 + cg * 8]
                          : make_uint4(0u, 0u, 0u, 0u);
        }
    };
    auto writeA = [&](int b, const float4 (&qf)[2], const uint4& qb) {
        if constexpr (A_F32) {
            #pragma unroll
            for (int i = 0; i < 2; ++i) {
                const int s = i * 512 + tid;
                const int row = s >> 3, cg = s & 7;
                bf16x4 p = { (__bf16)qf[i].x, (__bf16)qf[i].y,
                             (__bf16)qf[i].z, (__bf16)qf[i].w };
                *(bf16x4*)&sA[b][row * LDK + cg * 4] = p;
            }
        } else {
            const int row = tid >> 2, cg = tid & 3;
            *(uint4*)&sA[b][row * LDK + cg * 8] = qb;
        }
    };
    auto loadB = [&](int kt, uint4 (&qB)[2]) {
        const int k0 = kt * BK;
        #pragma unroll
        for (int i = 0; i < 2; ++i) {
            const int s = i * 512 + tid;              // 0..1023
            const int row = s >> 2, cg = s & 3;       // 256 rows x 4 bf16x8
            qB[i] = *(const uint4*)&Bb[(size_t)(n0 + row) * K + k0 + cg * 8];
        }
    };
    auto writeB = [&](int b, const uint4 (&qB)[2]) {
        #pragma unroll
        for (int i = 0; i < 2; ++i) {
            const int s = i * 512 + tid;
            const int row = s >> 2, cg = s & 3;
            *(uint4*)&sB[b][row * LDK + cg * 8] = qB[i];
        }
    };
    auto step = [&](int b) {
        bf16x8 bfr[4];
        #pragma unroll
        for (int n = 0; n < 4; ++n)
            bfr[n] = *(const bf16x8*)&sB[b][(wn * 64 + n * 16 + r16) * LDK + half * 8];
        #pragma unroll
        for (int m = 0; m < 4; ++m) {
            const bf16x8 afr = *(const bf16x8*)&sA[b][(wm * 64 + m * 16 + r16) * LDK + half * 8];
            #pragma unroll
            for (int n = 0; n < 4; ++n)
                acc[m][n] = __builtin_amdgcn_mfma_f32_16x16x32_bf16(
                                afr, bfr[n], acc[m][n], 0, 0, 0);
        }
    };
    auto syncb = [&]() {
        asm volatile("s_waitcnt lgkmcnt(0)" ::: "memory");
        __builtin_amdgcn_s_barrier();
        asm volatile("" ::: "memory");
    };

    // prologue: stage tile 0; tile-1 loads stay in flight across the barrier
    loadB(0, qB0); loadA(0, qf0, qb0);
    loadB(1, qB1); loadA(1, qf1, qb1);
    writeA(0, qf0, qb0); writeB(0, qB0);
    syncb();

    for (int t = 0; t < nkt; t += 2) {
        // compute tile t (buf0); stage t+1 (buf1); issue t+2 loads
        if (t + 2 < nkt) { loadA(t + 2, qf0, qb0); loadB(t + 2, qB0); }
        step(0);
        writeA(1, qf1, qb1); writeB(1, qB1);
        syncb();
        if (t + 2 < nkt) {
            // compute tile t+1 (buf1); stage t+2 (buf0); issue t+3 loads
            if (t + 3 < nkt) { loadA(t + 3, qf1, qb1); loadB(t + 3, qB1); }
            step(1);
            writeA(0, qf0, qb0); writeB(0, qB0);
            syncb();
        } else {
            step(1);
        }
    }

    // epilogue: C/D layout col=lane&15, row=(lane>>4)*4+j (m89-verified)
    #pragma unroll
    for (int m = 0; m < 4; ++m) {
        const int rbase = m0 + wm * 64 + m * 16 + half * 4;
        #pragma unroll
        for (int j = 0; j < 4; ++j) {
            const int gr = rbase + j;
            if (gr >= M) continue;
            #pragma unroll
            for (int n = 0; n < 4; ++n) {
                const int gc = n0 + wn * 64 + n * 16 + r16;
                float o = acc[m][n][j];
                if constexpr (BIAS) o += bias[gc];
                if constexpr (OUT_BF16)
                    ((__bf16*)Craw)[(size_t)gr * N + gc] = (__bf16)o;
                else
                    ((float*)Craw)[(size_t)gr * N + gc] = o;
            }
        }
    }
}

// ---------------------------------------------------------------------------
// CSR build: histogram -> exclusive scan (seeds cursor) -> fill
// ---------------------------------------------------------------------------
__global__ __launch_bounds__(256) void row_histogram(
    const int* __restrict__ arow, int* __restrict__ cnt, int E)
{
    const int t = blockIdx.x * blockDim.x + threadIdx.x;
    const int n = gridDim.x * blockDim.x;
    for (int e = t; e < E; e += n)
        atomicAdd(&cnt[arow[e]], 1);
}

__global__ __launch_bounds__(1024) void exscan(
    int* __restrict__ cnt_cur, int* __restrict__ ptr, int n)
{
    __shared__ int s[1024];
    const int t = threadIdx.x;
    const int chunk = (n + 1023) / 1024;
    const int base  = t * chunk;
    int sum = 0;
    for (int i = 0; i < chunk; ++i) {
        const int idx = base + i;
        if (idx < n) sum += cnt_cur[idx];
    }
    s[t] = sum;
    __syncthreads();
    for (int off = 1; off < 1024; off <<= 1) {
        int v = (t >= off) ? s[t - off] : 0;
        __syncthreads();
        s[t] += v;
        __syncthreads();
    }
    int run = (t == 0) ? 0 : s[t - 1];
    for (int i = 0; i < chunk; ++i) {
        const int idx = base + i;
        if (idx < n) {
            const int c = cnt_cur[idx];
            ptr[idx] = run;
            cnt_cur[idx] = run;   // cursor seed
            run += c;
        }
    }
    if (t == 1023) ptr[n] = run;
}

__global__ __launch_bounds__(256) void csr_fill(
    const int*   __restrict__ arow,
    const int*   __restrict__ acol,
    const float* __restrict__ aval,
    int*         __restrict__ cursor,   // seeded with start offsets
    int2*        __restrict__ cpair,    // {col, val-bits}
    int E)
{
    const int t = blockIdx.x * blockDim.x + threadIdx.x;
    const int n = gridDim.x * blockDim.x;
    for (int e = t; e < E; e += n) {
        const int pos = atomicAdd(&cursor[arow[e]], 1);
        cpair[pos] = make_int2(acol[e], __float_as_int(aval[e]));
    }
}

// ---------------------------------------------------------------------------
// SpMM gather + relu, bf16 support -> bf16 agg. One wave per row.
// ---------------------------------------------------------------------------
__global__ __launch_bounds__(256) void spmm_gather(
    const int*    __restrict__ ptr,
    const int2*   __restrict__ cpair,
    const __bf16* __restrict__ support,
    __bf16*       __restrict__ agg,
    int n)
{
    const int lane = threadIdx.x & 63;
    const int row  = blockIdx.x * 4 + (threadIdx.x >> 6);
    if (row >= n) return;
    const int beg = ptr[row], end = ptr[row + 1];

    f32x4 acc = {0.f, 0.f, 0.f, 0.f};
    int i = beg;
    for (; i + 8 <= end; i += 8) {
        #pragma unroll
        for (int u = 0; u < 8; ++u) {
            const int2  p = cpair[i + u];
            const float v = __int_as_float(p.y);
            const ushort4 s = *(const ushort4*)&support[(size_t)p.x * HID + lane * 4];
            acc.x += v * bf2f(s.x);
            acc.y += v * bf2f(s.y);
            acc.z += v * bf2f(s.z);
            acc.w += v * bf2f(s.w);
        }
    }
    for (; i < end; ++i) {
        const int2  p = cpair[i];
        const float v = __int_as_float(p.y);
        const ushort4 s = *(const ushort4*)&support[(size_t)p.x * HID + lane * 4];
        acc.x += v * bf2f(s.x);
        acc.y += v * bf2f(s.y);
        acc.z += v * bf2f(s.z);
        acc.w += v * bf2f(s.w);
    }
    bf16x4 o = { (__bf16)fmaxf(acc.x, 0.f), (__bf16)fmaxf(acc.y, 0.f),
                 (__bf16)fmaxf(acc.z, 0.f), (__bf16)fmaxf(acc.w, 0.f) };
    *(bf16x4*)&agg[(size_t)row * HID + lane * 4] = o;
}

extern "C" void kernel_launch(void* const* d_in, const int* in_sizes, int n_in,
                              void* d_out, int out_size, void* d_ws, size_t ws_size,
                              hipStream_t stream) {
    const float* context  = (const float*)d_in[0];
    const int*   adj_row  = (const int*)  d_in[1];
    const int*   adj_col  = (const int*)  d_in[2];
    const float* adj_val  = (const float*)d_in[3];
    const float* ctx_w    = (const float*)d_in[4];
    const float* out_w    = (const float*)d_in[5];
    const float* out_b    = (const float*)d_in[6];
    float*       out      = (float*)d_out;

    char* ws = (char*)d_ws;
    __bf16* support_b = (__bf16*)ws;  ws += (size_t)N_NODES * HID * 2;
    __bf16* agg_b     = (__bf16*)ws;  ws += (size_t)N_NODES * HID * 2;
    __bf16* ctxw_b    = (__bf16*)ws;  ws += (size_t)HID * VOCAB * 2;
    __bf16* outw_b    = (__bf16*)ws;  ws += (size_t)VOCAB * HID * 2;
    int*    csr_ptr   = (int*)ws;     ws += ((size_t)N_NODES + 16) * 4;
    int*    cursor    = (int*)ws;     ws += (size_t)N_NODES * 4;
    int2*   cpair     = (int2*)ws;    ws += (size_t)N_EDGES * 8;

    constexpr int MT = (N_NODES + 127) / 128;   // 391 m-tiles

    // weight preconverts
    cvt_f32_bf16<<<(HID * VOCAB / 4 + 255) / 256, 256, 0, stream>>>(
        ctx_w, ctxw_b, HID * VOCAB / 4);
    cvt_f32_bf16<<<(VOCAB * HID / 4 + 255) / 256, 256, 0, stream>>>(
        out_w, outw_b, VOCAB * HID / 4);

    // GEMM1: support_b = bf16( context @ ctx_w^T )  (M=50000, N=256, K=2048)
    gemm_p2<true, true, false><<<dim3(MT), dim3(512), 0, stream>>>(
        context, ctxw_b, nullptr, support_b, N_NODES, HID, VOCAB, 1);

    // CSR build
    hipMemsetAsync(cursor, 0, (size_t)N_NODES * 4, stream);
    row_histogram<<<1024, 256, 0, stream>>>(adj_row, cursor, N_EDGES);
    exscan<<<1, 1024, 0, stream>>>(cursor, csr_ptr, N_NODES);
    csr_fill<<<1024, 256, 0, stream>>>(
        adj_row, adj_col, adj_val, cursor, cpair, N_EDGES);

    // SpMM gather + relu -> agg_b
    spmm_gather<<<(N_NODES + 3) / 4, 256, 0, stream>>>(
        csr_ptr, cpair, support_b, agg_b, N_NODES);

    // GEMM2: out = agg_b @ out_w^T + b  (M=50000, N=2048, K=256)
    gemm_p2<false, false, true><<<dim3(MT * 8), dim3(512), 0, stream>>>(
        agg_b, outw_b, out_b, out, N_NODES, VOCAB, HID, 8);
}

// Round 7
// 711.862 us; speedup vs baseline: 2.5099x; 2.5099x over previous
//
#include <hip/hip_runtime.h>
#include <hip/hip_bf16.h>

#define N_NODES 50000
#define VOCAB   2048
#define HID     256
#define N_EDGES 1600000

typedef __attribute__((ext_vector_type(8))) __bf16 bf16x8;
typedef __attribute__((ext_vector_type(4))) __bf16 bf16x4;
typedef __attribute__((ext_vector_type(4))) float  f32x4;

__device__ __forceinline__ float bf2f(unsigned short u) {
    return __uint_as_float(((unsigned)u) << 16);
}

// async global->LDS, 16B per lane (HW: lds dst = wave-uniform base + lane*16)
__device__ __forceinline__ void gl_lds16(const void* g, void* l) {
    __builtin_amdgcn_global_load_lds(
        (const __attribute__((address_space(1))) void*)g,
        (__attribute__((address_space(3))) void*)l, 16, 0, 0);
}

// ---------------------------------------------------------------------------
// one-time fp32 -> bf16 weight preconvert (2 MB total)
// ---------------------------------------------------------------------------
__global__ __launch_bounds__(256) void cvt_f32_bf16(
    const float* __restrict__ in, __bf16* __restrict__ out, int n4)
{
    const int t = blockIdx.x * 256 + threadIdx.x;
    if (t < n4) {
        const float4 v = ((const float4*)in)[t];
        bf16x4 p = { (__bf16)v.x, (__bf16)v.y, (__bf16)v.z, (__bf16)v.w };
        ((bf16x4*)out)[t] = p;
    }
}

// ---------------------------------------------------------------------------
// GEMM1: support_b[M][256] = bf16( A_f32[M][2048] @ Bb[256][2048]^T )
// m97 structure: BM=64, BN=256, BK=64, 256 thr / 4 waves (1x4, 64x64 each),
// global_load_lds w16, single-buffer LDS, 2 barriers/tile.
// A staged as fp32 (cvt at frag read). XOR source-swizzle (rule 21):
//   A: 32B units, u ^= row&7 ; B: 16B chunks, c ^= row&7.
// ---------------------------------------------------------------------------
__global__ __launch_bounds__(256) void gemm1(
    const float*  __restrict__ Af,    // [M][2048] fp32
    const __bf16* __restrict__ Bb,    // [256][2048] bf16
    __bf16*       __restrict__ Cb,    // [M][256] bf16
    int M)
{
    constexpr int K = 2048, N = 256, BM = 64, BK = 64;
    __shared__ float  sAf[BM * BK];        // 16 KB
    __shared__ __bf16 sB[N * BK];          // 32 KB   (48 KB total)

    const int tid  = threadIdx.x;
    const int lane = tid & 63;
    const int wn   = tid >> 6;        // 0..3 (col-wave)
    const int half = lane >> 4;       // 0..3
    const int r16  = lane & 15;

    const int m0 = blockIdx.x * BM;

    f32x4 acc[4][4] = {};

    for (int kt = 0; kt < K / BK; ++kt) {
        const int k0 = kt * BK;
        // --- stage A: 64 rows x 16 chunks(16B) = 1024 -> 4 gl_lds/thread ---
        #pragma unroll
        for (int i = 0; i < 4; ++i) {
            const int s   = i * 256 + tid;
            const int row = s >> 4, c = s & 15;
            const int csw = (((c >> 1) ^ (row & 7)) << 1) | (c & 1);
            int gr = m0 + row; if (gr >= M) gr = M - 1;   // per-lane clamp
            gl_lds16(&Af[(size_t)gr * K + k0 + csw * 4], &sAf[s * 4]);
        }
        // --- stage B: 256 rows x 8 chunks(16B) = 2048 -> 8 gl_lds/thread ---
        #pragma unroll
        for (int i = 0; i < 8; ++i) {
            const int s   = i * 256 + tid;
            const int row = s >> 3, c = s & 7;
            const int csw = c ^ (row & 7);
            gl_lds16(&Bb[(size_t)row * K + k0 + csw * 8], &sB[s * 8]);
        }
        __syncthreads();   // vmcnt(0)+lgkmcnt(0)+barrier: LDS tile ready

        #pragma unroll
        for (int kk = 0; kk < 2; ++kk) {
            const int q = kk * 4 + half;           // logical chunk/unit
            bf16x8 bfr[4];
            #pragma unroll
            for (int n = 0; n < 4; ++n) {
                const int brow = wn * 64 + n * 16 + r16;
                bfr[n] = *(const bf16x8*)&sB[brow * 64 + (q ^ (brow & 7)) * 8];
            }
            #pragma unroll
            for (int m = 0; m < 4; ++m) {
                const int arow = m * 16 + r16;
                const int au   = q ^ (arow & 7);
                const f32x4 lo = *(const f32x4*)&sAf[arow * 64 + au * 8];
                const f32x4 hi = *(const f32x4*)&sAf[arow * 64 + au * 8 + 4];
                const bf16x8 af = { (__bf16)lo.x, (__bf16)lo.y, (__bf16)lo.z, (__bf16)lo.w,
                                    (__bf16)hi.x, (__bf16)hi.y, (__bf16)hi.z, (__bf16)hi.w };
                #pragma unroll
                for (int n = 0; n < 4; ++n)
                    acc[m][n] = __builtin_amdgcn_mfma_f32_16x16x32_bf16(
                                    af, bfr[n], acc[m][n], 0, 0, 0);
            }
        }
        __syncthreads();   // protect LDS before next tile's staging
    }

    // epilogue: C/D layout col=lane&15, row=(lane>>4)*4+j (m89-verified)
    #pragma unroll
    for (int m = 0; m < 4; ++m) {
        #pragma unroll
        for (int j = 0; j < 4; ++j) {
            const int gr = m0 + m * 16 + half * 4 + j;
            if (gr >= M) continue;
            #pragma unroll
            for (int n = 0; n < 4; ++n) {
                const int gc = wn * 64 + n * 16 + r16;
                Cb[(size_t)gr * N + gc] = (__bf16)acc[m][n][j];
            }
        }
    }
}

// ---------------------------------------------------------------------------
// GEMM2: out[M][2048] = Ab[M][256] @ Bb[2048][256]^T + bias
// m97 structure: BM=128, BN=128, BK=64, 256 thr / 4 waves (2x2, 64x64 each),
// gl_lds w16, single-buffer, XOR chunk-swizzle, XCD-chunked block swizzle.
// ---------------------------------------------------------------------------
__global__ __launch_bounds__(256) void gemm2(
    const __bf16* __restrict__ Ab,    // [M][256] bf16
    const __bf16* __restrict__ Bb,    // [2048][256] bf16
    const float*  __restrict__ bias,  // [2048]
    float*        __restrict__ C,     // [M][2048] fp32
    int M)
{
    constexpr int K = 256, N = 2048, BM = 128, BN = 128, BK = 64, NBY = N / BN;
    __shared__ __bf16 sA[BM * BK];    // 16 KB
    __shared__ __bf16 sB[BN * BK];    // 16 KB  (32 KB total)

    const int tid  = threadIdx.x;
    const int lane = tid & 63;
    const int wid  = tid >> 6;
    const int wm   = wid >> 1;        // 0..1
    const int wn   = wid & 1;         // 0..1
    const int half = lane >> 4;
    const int r16  = lane & 15;

    // XCD-chunked swizzle (grid divisible by 8)
    const int nwg = gridDim.x, cpx = nwg >> 3;
    const int wg  = (blockIdx.x & 7) * cpx + (blockIdx.x >> 3);
    const int m0  = (wg / NBY) * BM;
    const int n0  = (wg % NBY) * BN;

    f32x4 acc[4][4] = {};

    for (int kt = 0; kt < K / BK; ++kt) {
        const int k0 = kt * BK;
        // stage A,B: each 128 rows x 8 chunks(16B) = 1024 -> 4 gl_lds each
        #pragma unroll
        for (int i = 0; i < 4; ++i) {
            const int s   = i * 256 + tid;
            const int row = s >> 3, c = s & 7;
            const int csw = c ^ (row & 7);
            int gr = m0 + row; if (gr >= M) gr = M - 1;   // per-lane clamp
            gl_lds16(&Ab[(size_t)gr * K + k0 + csw * 8], &sA[s * 8]);
        }
        #pragma unroll
        for (int i = 0; i < 4; ++i) {
            const int s   = i * 256 + tid;
            const int row = s >> 3, c = s & 7;
            const int csw = c ^ (row & 7);
            gl_lds16(&Bb[(size_t)(n0 + row) * K + k0 + csw * 8], &sB[s * 8]);
        }
        __syncthreads();

        #pragma unroll
        for (int kk = 0; kk < 2; ++kk) {
            const int q = kk * 4 + half;
            bf16x8 bfr[4];
            #pragma unroll
            for (int n = 0; n < 4; ++n) {
                const int brow = wn * 64 + n * 16 + r16;
                bfr[n] = *(const bf16x8*)&sB[brow * 64 + (q ^ (brow & 7)) * 8];
            }
            #pragma unroll
            for (int m = 0; m < 4; ++m) {
                const int arow = wm * 64 + m * 16 + r16;
                const bf16x8 af = *(const bf16x8*)&sA[arow * 64 + (q ^ (arow & 7)) * 8];
                #pragma unroll
                for (int n = 0; n < 4; ++n)
                    acc[m][n] = __builtin_amdgcn_mfma_f32_16x16x32_bf16(
                                    af, bfr[n], acc[m][n], 0, 0, 0);
            }
        }
        __syncthreads();
    }

    #pragma unroll
    for (int m = 0; m < 4; ++m) {
        #pragma unroll
        for (int j = 0; j < 4; ++j) {
            const int gr = m0 + wm * 64 + m * 16 + half * 4 + j;
            if (gr >= M) continue;
            #pragma unroll
            for (int n = 0; n < 4; ++n) {
                const int gc = n0 + wn * 64 + n * 16 + r16;
                C[(size_t)gr * N + gc] = acc[m][n][j] + bias[gc];
            }
        }
    }
}

// ---------------------------------------------------------------------------
// CSR build: histogram -> exclusive scan (seeds cursor) -> fill
// ---------------------------------------------------------------------------
__global__ __launch_bounds__(256) void row_histogram(
    const int* __restrict__ arow, int* __restrict__ cnt, int E)
{
    const int t = blockIdx.x * blockDim.x + threadIdx.x;
    const int n = gridDim.x * blockDim.x;
    for (int e = t; e < E; e += n)
        atomicAdd(&cnt[arow[e]], 1);
}

__global__ __launch_bounds__(1024) void exscan(
    int* __restrict__ cnt_cur, int* __restrict__ ptr, int n)
{
    __shared__ int s[1024];
    const int t = threadIdx.x;
    const int chunk = (n + 1023) / 1024;
    const int base  = t * chunk;
    int sum = 0;
    for (int i = 0; i < chunk; ++i) {
        const int idx = base + i;
        if (idx < n) sum += cnt_cur[idx];
    }
    s[t] = sum;
    __syncthreads();
    for (int off = 1; off < 1024; off <<= 1) {
        int v = (t >= off) ? s[t - off] : 0;
        __syncthreads();
        s[t] += v;
        __syncthreads();
    }
    int run = (t == 0) ? 0 : s[t - 1];
    for (int i = 0; i < chunk; ++i) {
        const int idx = base + i;
        if (idx < n) {
            const int c = cnt_cur[idx];
            ptr[idx] = run;
            cnt_cur[idx] = run;   // cursor seed
            run += c;
        }
    }
    if (t == 1023) ptr[n] = run;
}

__global__ __launch_bounds__(256) void csr_fill(
    const int*   __restrict__ arow,
    const int*   __restrict__ acol,
    const float* __restrict__ aval,
    int*         __restrict__ cursor,   // seeded with start offsets
    int2*        __restrict__ cpair,    // {col, val-bits}
    int E)
{
    const int t = blockIdx.x * blockDim.x + threadIdx.x;
    const int n = gridDim.x * blockDim.x;
    for (int e = t; e < E; e += n) {
        const int pos = atomicAdd(&cursor[arow[e]], 1);
        cpair[pos] = make_int2(acol[e], __float_as_int(aval[e]));
    }
}

// ---------------------------------------------------------------------------
// SpMM gather + relu, bf16 support -> bf16 agg. One wave per row.
// ---------------------------------------------------------------------------
__global__ __launch_bounds__(256) void spmm_gather(
    const int*    __restrict__ ptr,
    const int2*   __restrict__ cpair,
    const __bf16* __restrict__ support,
    __bf16*       __restrict__ agg,
    int n)
{
    const int lane = threadIdx.x & 63;
    const int row  = blockIdx.x * 4 + (threadIdx.x >> 6);
    if (row >= n) return;
    const int beg = ptr[row], end = ptr[row + 1];

    f32x4 acc = {0.f, 0.f, 0.f, 0.f};
    int i = beg;
    for (; i + 8 <= end; i += 8) {
        #pragma unroll
        for (int u = 0; u < 8; ++u) {
            const int2  p = cpair[i + u];
            const float v = __int_as_float(p.y);
            const ushort4 s = *(const ushort4*)&support[(size_t)p.x * HID + lane * 4];
            acc.x += v * bf2f(s.x);
            acc.y += v * bf2f(s.y);
            acc.z += v * bf2f(s.z);
            acc.w += v * bf2f(s.w);
        }
    }
    for (; i < end; ++i) {
        const int2  p = cpair[i];
        const float v = __int_as_float(p.y);
        const ushort4 s = *(const ushort4*)&support[(size_t)p.x * HID + lane * 4];
        acc.x += v * bf2f(s.x);
        acc.y += v * bf2f(s.y);
        acc.z += v * bf2f(s.z);
        acc.w += v * bf2f(s.w);
    }
    bf16x4 o = { (__bf16)fmaxf(acc.x, 0.f), (__bf16)fmaxf(acc.y, 0.f),
                 (__bf16)fmaxf(acc.z, 0.f), (__bf16)fmaxf(acc.w, 0.f) };
    *(bf16x4*)&agg[(size_t)row * HID + lane * 4] = o;
}

extern "C" void kernel_launch(void* const* d_in, const int* in_sizes, int n_in,
                              void* d_out, int out_size, void* d_ws, size_t ws_size,
                              hipStream_t stream) {
    const float* context  = (const float*)d_in[0];
    const int*   adj_row  = (const int*)  d_in[1];
    const int*   adj_col  = (const int*)  d_in[2];
    const float* adj_val  = (const float*)d_in[3];
    const float* ctx_w    = (const float*)d_in[4];
    const float* out_w    = (const float*)d_in[5];
    const float* out_b    = (const float*)d_in[6];
    float*       out      = (float*)d_out;

    char* ws = (char*)d_ws;
    __bf16* support_b = (__bf16*)ws;  ws += (size_t)N_NODES * HID * 2;
    __bf16* agg_b     = (__bf16*)ws;  ws += (size_t)N_NODES * HID * 2;
    __bf16* ctxw_b    = (__bf16*)ws;  ws += (size_t)HID * VOCAB * 2;
    __bf16* outw_b    = (__bf16*)ws;  ws += (size_t)VOCAB * HID * 2;
    int*    csr_ptr   = (int*)ws;     ws += ((size_t)N_NODES + 16) * 4;
    int*    cursor    = (int*)ws;     ws += (size_t)N_NODES * 4;
    int2*   cpair     = (int2*)ws;    ws += (size_t)N_EDGES * 8;

    // weight preconverts
    cvt_f32_bf16<<<(HID * VOCAB / 4 + 255) / 256, 256, 0, stream>>>(
        ctx_w, ctxw_b, HID * VOCAB / 4);
    cvt_f32_bf16<<<(VOCAB * HID / 4 + 255) / 256, 256, 0, stream>>>(
        out_w, outw_b, VOCAB * HID / 4);

    // GEMM1: support_b = bf16( context @ ctx_w^T )
    gemm1<<<dim3((N_NODES + 63) / 64), dim3(256), 0, stream>>>(
        context, ctxw_b, support_b, N_NODES);

    // CSR build
    hipMemsetAsync(cursor, 0, (size_t)N_NODES * 4, stream);
    row_histogram<<<1024, 256, 0, stream>>>(adj_row, cursor, N_EDGES);
    exscan<<<1, 1024, 0, stream>>>(cursor, csr_ptr, N_NODES);
    csr_fill<<<1024, 256, 0, stream>>>(
        adj_row, adj_col, adj_val, cursor, cpair, N_EDGES);

    // SpMM gather + relu -> agg_b
    spmm_gather<<<(N_NODES + 3) / 4, 256, 0, stream>>>(
        csr_ptr, cpair, support_b, agg_b, N_NODES);

    // GEMM2: out = agg_b @ out_w^T + b
    gemm2<<<dim3(((N_NODES + 127) / 128) * (VOCAB / 128)), dim3(256), 0, stream>>>(
        agg_b, outw_b, out_b, out, N_NODES);
}

// Round 8
// 659.524 us; speedup vs baseline: 2.7090x; 1.0794x over previous
//
#include <hip/hip_runtime.h>
#include <hip/hip_bf16.h>

#define N_NODES 50000
#define VOCAB   2048
#define HID     256
#define N_EDGES 1600000

typedef __attribute__((ext_vector_type(8))) __bf16 bf16x8;
typedef __attribute__((ext_vector_type(4))) __bf16 bf16x4;
typedef __attribute__((ext_vector_type(4))) float  f32x4;

__device__ __forceinline__ float bf2f(unsigned short u) {
    return __uint_as_float(((unsigned)u) << 16);
}

// async global->LDS, 16B per lane (HW: lds dst = wave-uniform base + lane*16)
__device__ __forceinline__ void gl_lds16(const void* g, void* l) {
    __builtin_amdgcn_global_load_lds(
        (const __attribute__((address_space(1))) void*)g,
        (__attribute__((address_space(3))) void*)l, 16, 0, 0);
}

// ---------------------------------------------------------------------------
// one-time fp32 -> bf16 weight preconvert (2 MB total)
// ---------------------------------------------------------------------------
__global__ __launch_bounds__(256) void cvt_f32_bf16(
    const float* __restrict__ in, __bf16* __restrict__ out, int n4)
{
    const int t = blockIdx.x * 256 + threadIdx.x;
    if (t < n4) {
        const float4 v = ((const float4*)in)[t];
        bf16x4 p = { (__bf16)v.x, (__bf16)v.y, (__bf16)v.z, (__bf16)v.w };
        ((bf16x4*)out)[t] = p;
    }
}

// ---------------------------------------------------------------------------
// GEMM1: support_b[M][256] = bf16( A_f32[M][2048] @ Bb[256][2048]^T )
// BM=64, BN=256, BK=32, 4 waves (1x4, 64x64), double-buffered gl_lds,
// ONE barrier per K-tile: stage(t+1)->buf^1, mfma(buf), sync.
// A fp32 chunks(16B) XOR row&7 (conflict-free); B bf16 chunks XOR row&3.
// ---------------------------------------------------------------------------
__global__ __launch_bounds__(256) void gemm1(
    const float*  __restrict__ Af,    // [M][2048] fp32
    const __bf16* __restrict__ Bb,    // [256][2048] bf16
    __bf16*       __restrict__ Cb,    // [M][256] bf16
    int M)
{
    constexpr int K = 2048, N = 256, BM = 64, BK = 32;
    __shared__ float  sAf[2][BM * BK];     // 2 x  8 KB
    __shared__ __bf16 sB [2][N  * BK];     // 2 x 16 KB  (48 KB total)

    const int tid  = threadIdx.x;
    const int lane = tid & 63;
    const int wn   = tid >> 6;        // 0..3 (col-wave)
    const int half = lane >> 4;       // 0..3
    const int r16  = lane & 15;

    const int m0 = blockIdx.x * BM;

    f32x4 acc[4][4] = {};

    auto stage = [&](int kt, int b) {
        const int k0 = kt * BK;
        // A: 64 rows x 8 chunks(16B) = 512 -> 2 gl_lds/thread
        #pragma unroll
        for (int i = 0; i < 2; ++i) {
            const int s   = i * 256 + tid;
            const int row = s >> 3, c = s & 7;
            const int csw = c ^ (row & 7);
            int gr = m0 + row; if (gr >= M) gr = M - 1;
            gl_lds16(&Af[(size_t)gr * K + k0 + csw * 4], &sAf[b][s * 4]);
        }
        // B: 256 rows x 4 chunks(16B) = 1024 -> 4 gl_lds/thread
        #pragma unroll
        for (int i = 0; i < 4; ++i) {
            const int s   = i * 256 + tid;
            const int row = s >> 2, c = s & 3;
            const int csw = c ^ (row & 3);
            gl_lds16(&Bb[(size_t)row * K + k0 + csw * 8], &sB[b][s * 8]);
        }
    };
    auto step = [&](int b) {
        bf16x8 bfr[4];
        #pragma unroll
        for (int n = 0; n < 4; ++n) {
            const int brow = wn * 64 + n * 16 + r16;
            bfr[n] = *(const bf16x8*)&sB[b][brow * 32 + (half ^ (brow & 3)) * 8];
        }
        #pragma unroll
        for (int m = 0; m < 4; ++m) {
            const int arow = m * 16 + r16;
            const int rx   = arow & 7;
            const f32x4 lo = *(const f32x4*)&sAf[b][arow * 32 + ((2 * half)     ^ rx) * 4];
            const f32x4 hi = *(const f32x4*)&sAf[b][arow * 32 + ((2 * half + 1) ^ rx) * 4];
            const bf16x8 af = { (__bf16)lo.x, (__bf16)lo.y, (__bf16)lo.z, (__bf16)lo.w,
                                (__bf16)hi.x, (__bf16)hi.y, (__bf16)hi.z, (__bf16)hi.w };
            #pragma unroll
            for (int n = 0; n < 4; ++n)
                acc[m][n] = __builtin_amdgcn_mfma_f32_16x16x32_bf16(
                                af, bfr[n], acc[m][n], 0, 0, 0);
        }
    };

    stage(0, 0);
    __syncthreads();
    constexpr int nkt = K / BK;     // 64
    for (int kt = 0; kt < nkt; ++kt) {
        const int cur = kt & 1;
        if (kt + 1 < nkt) stage(kt + 1, cur ^ 1);
        step(cur);
        __syncthreads();    // drains vmcnt(0): next buffer ready; this buffer free
    }

    // epilogue: C/D layout col=lane&15, row=(lane>>4)*4+j (m89-verified)
    #pragma unroll
    for (int m = 0; m < 4; ++m) {
        #pragma unroll
        for (int j = 0; j < 4; ++j) {
            const int gr = m0 + m * 16 + half * 4 + j;
            if (gr >= M) continue;
            #pragma unroll
            for (int n = 0; n < 4; ++n) {
                const int gc = wn * 64 + n * 16 + r16;
                Cb[(size_t)gr * N + gc] = (__bf16)acc[m][n][j];
            }
        }
    }
}

// ---------------------------------------------------------------------------
// GEMM2: out[M][2048] = Ab[M][256] @ Bb[2048][256]^T + bias
// BM=128, BN=128, BK=32, 4 waves (2x2, 64x64), dbuf gl_lds, 1 barrier/tile,
// 32 KB LDS -> 5 blocks/CU. XCD-chunked block swizzle (grid % 8 == 0).
// ---------------------------------------------------------------------------
__global__ __launch_bounds__(256) void gemm2(
    const __bf16* __restrict__ Ab,    // [M][256] bf16
    const __bf16* __restrict__ Bb,    // [2048][256] bf16
    const float*  __restrict__ bias,  // [2048]
    float*        __restrict__ C,     // [M][2048] fp32
    int M)
{
    constexpr int K = 256, N = 2048, BM = 128, BN = 128, BK = 32, NBY = N / BN;
    __shared__ __bf16 sA[2][BM * BK];   // 2 x 8 KB
    __shared__ __bf16 sB[2][BN * BK];   // 2 x 8 KB  (32 KB total)

    const int tid  = threadIdx.x;
    const int lane = tid & 63;
    const int wid  = tid >> 6;
    const int wm   = wid >> 1;        // 0..1
    const int wn   = wid & 1;         // 0..1
    const int half = lane >> 4;
    const int r16  = lane & 15;

    const int nwg = gridDim.x, cpx = nwg >> 3;
    const int wg  = (blockIdx.x & 7) * cpx + (blockIdx.x >> 3);
    const int m0  = (wg / NBY) * BM;
    const int n0  = (wg % NBY) * BN;

    f32x4 acc[4][4] = {};

    auto stage = [&](int kt, int b) {
        const int k0 = kt * BK;
        #pragma unroll
        for (int i = 0; i < 2; ++i) {       // A: 128 rows x 4 chunks = 512
            const int s   = i * 256 + tid;
            const int row = s >> 2, c = s & 3;
            const int csw = c ^ (row & 3);
            int gr = m0 + row; if (gr >= M) gr = M - 1;
            gl_lds16(&Ab[(size_t)gr * K + k0 + csw * 8], &sA[b][s * 8]);
        }
        #pragma unroll
        for (int i = 0; i < 2; ++i) {       // B: 128 rows x 4 chunks = 512
            const int s   = i * 256 + tid;
            const int row = s >> 2, c = s & 3;
            const int csw = c ^ (row & 3);
            gl_lds16(&Bb[(size_t)(n0 + row) * K + k0 + csw * 8], &sB[b][s * 8]);
        }
    };
    auto step = [&](int b) {
        bf16x8 bfr[4];
        #pragma unroll
        for (int n = 0; n < 4; ++n) {
            const int brow = wn * 64 + n * 16 + r16;
            bfr[n] = *(const bf16x8*)&sB[b][brow * 32 + (half ^ (brow & 3)) * 8];
        }
        #pragma unroll
        for (int m = 0; m < 4; ++m) {
            const int arow = wm * 64 + m * 16 + r16;
            const bf16x8 af = *(const bf16x8*)&sA[b][arow * 32 + (half ^ (arow & 3)) * 8];
            #pragma unroll
            for (int n = 0; n < 4; ++n)
                acc[m][n] = __builtin_amdgcn_mfma_f32_16x16x32_bf16(
                                af, bfr[n], acc[m][n], 0, 0, 0);
        }
    };

    stage(0, 0);
    __syncthreads();
    constexpr int nkt = K / BK;     // 8
    for (int kt = 0; kt < nkt; ++kt) {
        const int cur = kt & 1;
        if (kt + 1 < nkt) stage(kt + 1, cur ^ 1);
        step(cur);
        __syncthreads();
    }

    #pragma unroll
    for (int m = 0; m < 4; ++m) {
        #pragma unroll
        for (int j = 0; j < 4; ++j) {
            const int gr = m0 + wm * 64 + m * 16 + half * 4 + j;
            if (gr >= M) continue;
            #pragma unroll
            for (int n = 0; n < 4; ++n) {
                const int gc = n0 + wn * 64 + n * 16 + r16;
                C[(size_t)gr * N + gc] = acc[m][n][j] + bias[gc];
            }
        }
    }
}

// ---------------------------------------------------------------------------
// CSR build: histogram -> 3-phase coalesced scan (seeds cursor) -> fill
// ---------------------------------------------------------------------------
__global__ __launch_bounds__(256) void row_histogram(
    const int* __restrict__ arow, int* __restrict__ cnt, int E)
{
    const int t = blockIdx.x * blockDim.x + threadIdx.x;
    const int n = gridDim.x * blockDim.x;
    for (int e = t; e < E; e += n)
        atomicAdd(&cnt[arow[e]], 1);
}

#define SCAN_NB 49      // 49 blocks x 256 thr x 4 elems = 50176 >= 50000

__global__ __launch_bounds__(256) void scan1(
    const int* __restrict__ cnt, int* __restrict__ bsum, int n)
{
    __shared__ int red[256];
    const int base = blockIdx.x * 1024 + threadIdx.x * 4;
    int s = 0;
    #pragma unroll
    for (int i = 0; i < 4; ++i) { const int idx = base + i; if (idx < n) s += cnt[idx]; }
    red[threadIdx.x] = s;
    __syncthreads();
    for (int off = 128; off > 0; off >>= 1) {
        if (threadIdx.x < off) red[threadIdx.x] += red[threadIdx.x + off];
        __syncthreads();
    }
    if (threadIdx.x == 0) bsum[blockIdx.x] = red[0];
}

__global__ __launch_bounds__(64) void scan2(int* __restrict__ bsum, int nb)
{
    if (threadIdx.x == 0) {
        int run = 0;
        for (int b = 0; b < nb; ++b) { const int v = bsum[b]; bsum[b] = run; run += v; }
        bsum[nb] = run;
    }
}

__global__ __launch_bounds__(256) void scan3(
    const int* __restrict__ cnt, const int* __restrict__ bsum,
    int* __restrict__ ptr, int* __restrict__ cursor, int n)
{
    __shared__ int hs[256];
    const int base = blockIdx.x * 1024 + threadIdx.x * 4;
    int loc[4]; int s = 0;
    #pragma unroll
    for (int i = 0; i < 4; ++i) {
        const int idx = base + i;
        loc[i] = (idx < n) ? cnt[idx] : 0;
        s += loc[i];
    }
    hs[threadIdx.x] = s;
    __syncthreads();
    for (int off = 1; off < 256; off <<= 1) {
        int v = (threadIdx.x >= off) ? hs[threadIdx.x - off] : 0;
        __syncthreads();
        hs[threadIdx.x] += v;
        __syncthreads();
    }
    int run = bsum[blockIdx.x] + ((threadIdx.x == 0) ? 0 : hs[threadIdx.x - 1]);
    #pragma unroll
    for (int i = 0; i < 4; ++i) {
        const int idx = base + i;
        if (idx < n) { ptr[idx] = run; cursor[idx] = run; }
        run += loc[i];
    }
    if (blockIdx.x == SCAN_NB - 1 && threadIdx.x == 255) ptr[n] = run;
}

__global__ __launch_bounds__(256) void csr_fill(
    const int*   __restrict__ arow,
    const int*   __restrict__ acol,
    const float* __restrict__ aval,
    int*         __restrict__ cursor,   // seeded with start offsets
    int2*        __restrict__ cpair,    // {col, val-bits}
    int E)
{
    const int t = blockIdx.x * blockDim.x + threadIdx.x;
    const int n = gridDim.x * blockDim.x;
    for (int e = t; e < E; e += n) {
        const int pos = atomicAdd(&cursor[arow[e]], 1);
        cpair[pos] = make_int2(acol[e], __float_as_int(aval[e]));
    }
}

// ---------------------------------------------------------------------------
// SpMM gather + relu: one wave per row; 2 edges in flight (32 lanes x 16B
// each); __shfl_xor(32) fold; lanes 0-31 store bf16x8.
// ---------------------------------------------------------------------------
__global__ __launch_bounds__(256) void spmm_gather(
    const int*    __restrict__ ptr,
    const int2*   __restrict__ cpair,
    const __bf16* __restrict__ support,
    __bf16*       __restrict__ agg,
    int n)
{
    const int tid  = threadIdx.x;
    const int lane = tid & 63;
    const int row  = blockIdx.x * 4 + (tid >> 6);
    if (row >= n) return;
    const int l32 = lane & 31, ep = lane >> 5;
    const int beg = ptr[row], end = ptr[row + 1];

    float a[8] = {0.f, 0.f, 0.f, 0.f, 0.f, 0.f, 0.f, 0.f};

    auto fma_edge = [&](const int2 p) {
        const float v = __int_as_float(p.y);
        const uint4 s = *(const uint4*)&support[(size_t)p.x * HID + l32 * 8];
        a[0] += v * __uint_as_float(s.x << 16);
        a[1] += v * __uint_as_float(s.x & 0xFFFF0000u);
        a[2] += v * __uint_as_float(s.y << 16);
        a[3] += v * __uint_as_float(s.y & 0xFFFF0000u);
        a[4] += v * __uint_as_float(s.z << 16);
        a[5] += v * __uint_as_float(s.z & 0xFFFF0000u);
        a[6] += v * __uint_as_float(s.w << 16);
        a[7] += v * __uint_as_float(s.w & 0xFFFF0000u);
    };

    int i = beg;
    for (; i + 4 <= end; i += 4) {          // 2 pairs in flight
        const int2 p0 = cpair[i + ep];
        const int2 p1 = cpair[i + 2 + ep];
        fma_edge(p0);
        fma_edge(p1);
    }
    if (i + 2 <= end) { fma_edge(cpair[i + ep]); i += 2; }
    if (i < end && ep == 0) fma_edge(cpair[i]);   // odd tail: low half only

    // fold the two edge-groups (lane L <-> L+32), then lanes 0-31 store
    #pragma unroll
    for (int k = 0; k < 8; ++k) a[k] += __shfl_xor(a[k], 32);

    if (ep == 0) {
        bf16x8 o = { (__bf16)fmaxf(a[0], 0.f), (__bf16)fmaxf(a[1], 0.f),
                     (__bf16)fmaxf(a[2], 0.f), (__bf16)fmaxf(a[3], 0.f),
                     (__bf16)fmaxf(a[4], 0.f), (__bf16)fmaxf(a[5], 0.f),
                     (__bf16)fmaxf(a[6], 0.f), (__bf16)fmaxf(a[7], 0.f) };
        *(bf16x8*)&agg[(size_t)row * HID + l32 * 8] = o;
    }
}

extern "C" void kernel_launch(void* const* d_in, const int* in_sizes, int n_in,
                              void* d_out, int out_size, void* d_ws, size_t ws_size,
                              hipStream_t stream) {
    const float* context  = (const float*)d_in[0];
    const int*   adj_row  = (const int*)  d_in[1];
    const int*   adj_col  = (const int*)  d_in[2];
    const float* adj_val  = (const float*)d_in[3];
    const float* ctx_w    = (const float*)d_in[4];
    const float* out_w    = (const float*)d_in[5];
    const float* out_b    = (const float*)d_in[6];
    float*       out      = (float*)d_out;

    char* ws = (char*)d_ws;
    __bf16* support_b = (__bf16*)ws;  ws += (size_t)N_NODES * HID * 2;
    __bf16* agg_b     = (__bf16*)ws;  ws += (size_t)N_NODES * HID * 2;
    __bf16* ctxw_b    = (__bf16*)ws;  ws += (size_t)HID * VOCAB * 2;
    __bf16* outw_b    = (__bf16*)ws;  ws += (size_t)VOCAB * HID * 2;
    int*    csr_ptr   = (int*)ws;     ws += ((size_t)N_NODES + 16) * 4;
    int*    cnt       = (int*)ws;     ws += (size_t)N_NODES * 4;
    int*    cursor    = (int*)ws;     ws += (size_t)N_NODES * 4;
    int*    bsum      = (int*)ws;     ws += ((size_t)SCAN_NB + 16) * 4;
    int2*   cpair     = (int2*)ws;    ws += (size_t)N_EDGES * 8;

    // weight preconverts
    cvt_f32_bf16<<<(HID * VOCAB / 4 + 255) / 256, 256, 0, stream>>>(
        ctx_w, ctxw_b, HID * VOCAB / 4);
    cvt_f32_bf16<<<(VOCAB * HID / 4 + 255) / 256, 256, 0, stream>>>(
        out_w, outw_b, VOCAB * HID / 4);

    // GEMM1: support_b = bf16( context @ ctx_w^T )
    gemm1<<<dim3((N_NODES + 63) / 64), dim3(256), 0, stream>>>(
        context, ctxw_b, support_b, N_NODES);

    // CSR build
    hipMemsetAsync(cnt, 0, (size_t)N_NODES * 4, stream);
    row_histogram<<<1024, 256, 0, stream>>>(adj_row, cnt, N_EDGES);
    scan1<<<SCAN_NB, 256, 0, stream>>>(cnt, bsum, N_NODES);
    scan2<<<1, 64, 0, stream>>>(bsum, SCAN_NB);
    scan3<<<SCAN_NB, 256, 0, stream>>>(cnt, bsum, csr_ptr, cursor, N_NODES);
    csr_fill<<<1024, 256, 0, stream>>>(
        adj_row, adj_col, adj_val, cursor, cpair, N_EDGES);

    // SpMM gather + relu -> agg_b
    spmm_gather<<<(N_NODES + 3) / 4, 256, 0, stream>>>(
        csr_ptr, cpair, support_b, agg_b, N_NODES);

    // GEMM2: out = agg_b @ out_w^T + b
    gemm2<<<dim3(((N_NODES + 127) / 128) * (VOCAB / 128)), dim3(256), 0, stream>>>(
        agg_b, outw_b, out_b, out, N_NODES);
}

// Round 9
// 653.955 us; speedup vs baseline: 2.7321x; 1.0085x over previous
//
#include <hip/hip_runtime.h>
#include <hip/hip_bf16.h>

#define N_NODES 50000
#define VOCAB   2048
#define HID     256
#define N_EDGES 1600000

typedef __attribute__((ext_vector_type(8))) __bf16 bf16x8;
typedef __attribute__((ext_vector_type(4))) __bf16 bf16x4;
typedef __attribute__((ext_vector_type(4))) float  f32x4;

__device__ __forceinline__ float bf2f(unsigned short u) {
    return __uint_as_float(((unsigned)u) << 16);
}

// async global->LDS, 16B per lane (HW: lds dst = wave-uniform base + lane*16)
__device__ __forceinline__ void gl_lds16(const void* g, void* l) {
    __builtin_amdgcn_global_load_lds(
        (const __attribute__((address_space(1))) void*)g,
        (__attribute__((address_space(3))) void*)l, 16, 0, 0);
}

// ---------------------------------------------------------------------------
// one-time fp32 -> bf16 weight preconvert (2 MB total)
// ---------------------------------------------------------------------------
__global__ __launch_bounds__(256) void cvt_f32_bf16(
    const float* __restrict__ in, __bf16* __restrict__ out, int n4)
{
    const int t = blockIdx.x * 256 + threadIdx.x;
    if (t < n4) {
        const float4 v = ((const float4*)in)[t];
        bf16x4 p = { (__bf16)v.x, (__bf16)v.y, (__bf16)v.z, (__bf16)v.w };
        ((bf16x4*)out)[t] = p;
    }
}

// ---------------------------------------------------------------------------
// GEMM1: support_b[M][256] = bf16( A_f32[M][2048] @ Bb[256][2048]^T )
// BM=64, BN=256, BK=32, 4 waves (1x4, 64x64). TRIPLE-buffered gl_lds,
// counted vmcnt (T4): per tile {vmcnt(6) -> s_barrier -> MFMA(t%3) ->
// stage(t+2)}. Tile t+1's 6 loads stay in flight across the barrier.
// A fp32 chunks(16B) XOR row&7; B bf16 chunks XOR row&3 (rule 21 pair).
// ---------------------------------------------------------------------------
__global__ __launch_bounds__(256) void gemm1(
    const float*  __restrict__ Af,    // [M][2048] fp32
    const __bf16* __restrict__ Bb,    // [256][2048] bf16
    __bf16*       __restrict__ Cb,    // [M][256] bf16
    int M)
{
    constexpr int K = 2048, N = 256, BM = 64, BK = 32, nkt = K / BK;
    __shared__ float  sAf[3][BM * BK];     // 3 x  8 KB
    __shared__ __bf16 sB [3][N  * BK];     // 3 x 16 KB  (72 KB total)

    const int tid  = threadIdx.x;
    const int lane = tid & 63;
    const int wn   = tid >> 6;        // 0..3 (col-wave)
    const int half = lane >> 4;       // 0..3
    const int r16  = lane & 15;

    const int m0 = blockIdx.x * BM;

    f32x4 acc[4][4] = {};

    auto stage = [&](int kt, int b) {   // 6 gl_lds per thread
        const int k0 = kt * BK;
        // A: 64 rows x 8 chunks(16B) = 512 -> 2 gl_lds/thread
        #pragma unroll
        for (int i = 0; i < 2; ++i) {
            const int s   = i * 256 + tid;
            const int row = s >> 3, c = s & 7;
            const int csw = c ^ (row & 7);
            int gr = m0 + row; if (gr >= M) gr = M - 1;
            gl_lds16(&Af[(size_t)gr * K + k0 + csw * 4], &sAf[b][s * 4]);
        }
        // B: 256 rows x 4 chunks(16B) = 1024 -> 4 gl_lds/thread
        #pragma unroll
        for (int i = 0; i < 4; ++i) {
            const int s   = i * 256 + tid;
            const int row = s >> 2, c = s & 3;
            const int csw = c ^ (row & 3);
            gl_lds16(&Bb[(size_t)row * K + k0 + csw * 8], &sB[b][s * 8]);
        }
    };
    auto step = [&](int b) {
        bf16x8 bfr[4];
        #pragma unroll
        for (int n = 0; n < 4; ++n) {
            const int brow = wn * 64 + n * 16 + r16;
            bfr[n] = *(const bf16x8*)&sB[b][brow * 32 + (half ^ (brow & 3)) * 8];
        }
        #pragma unroll
        for (int m = 0; m < 4; ++m) {
            const int arow = m * 16 + r16;
            const int rx   = arow & 7;
            const f32x4 lo = *(const f32x4*)&sAf[b][arow * 32 + ((2 * half)     ^ rx) * 4];
            const f32x4 hi = *(const f32x4*)&sAf[b][arow * 32 + ((2 * half + 1) ^ rx) * 4];
            const bf16x8 af = { (__bf16)lo.x, (__bf16)lo.y, (__bf16)lo.z, (__bf16)lo.w,
                                (__bf16)hi.x, (__bf16)hi.y, (__bf16)hi.z, (__bf16)hi.w };
            #pragma unroll
            for (int n = 0; n < 4; ++n)
                acc[m][n] = __builtin_amdgcn_mfma_f32_16x16x32_bf16(
                                af, bfr[n], acc[m][n], 0, 0, 0);
        }
    };

    stage(0, 0);
    stage(1, 1);
    for (int t = 0; t < nkt; ++t) {
        if (t + 1 < nkt) asm volatile("s_waitcnt vmcnt(6)" ::: "memory");
        else             asm volatile("s_waitcnt vmcnt(0)" ::: "memory");
        __builtin_amdgcn_s_barrier();
        __builtin_amdgcn_sched_barrier(0);
        step(t % 3);
        if (t + 2 < nkt) stage(t + 2, (t + 2) % 3);
    }

    // epilogue: C/D layout col=lane&15, row=(lane>>4)*4+j (m89-verified)
    #pragma unroll
    for (int m = 0; m < 4; ++m) {
        #pragma unroll
        for (int j = 0; j < 4; ++j) {
            const int gr = m0 + m * 16 + half * 4 + j;
            if (gr >= M) continue;
            #pragma unroll
            for (int n = 0; n < 4; ++n) {
                const int gc = wn * 64 + n * 16 + r16;
                Cb[(size_t)gr * N + gc] = (__bf16)acc[m][n][j];
            }
        }
    }
}

// ---------------------------------------------------------------------------
// GEMM2: out[M][2048] = Ab[M][256] @ Bb[2048][256]^T + bias
// BM=128, BN=128, BK=32, 4 waves (2x2, 64x64). Triple-buffered gl_lds,
// counted vmcnt(4), raw barrier. 48 KB LDS -> 3 blocks/CU. XCD swizzle.
// ---------------------------------------------------------------------------
__global__ __launch_bounds__(256) void gemm2(
    const __bf16* __restrict__ Ab,    // [M][256] bf16
    const __bf16* __restrict__ Bb,    // [2048][256] bf16
    const float*  __restrict__ bias,  // [2048]
    float*        __restrict__ C,     // [M][2048] fp32
    int M)
{
    constexpr int K = 256, N = 2048, BM = 128, BN = 128, BK = 32;
    constexpr int NBY = N / BN, nkt = K / BK;
    __shared__ __bf16 sA[3][BM * BK];   // 3 x 8 KB
    __shared__ __bf16 sB[3][BN * BK];   // 3 x 8 KB  (48 KB total)

    const int tid  = threadIdx.x;
    const int lane = tid & 63;
    const int wid  = tid >> 6;
    const int wm   = wid >> 1;        // 0..1
    const int wn   = wid & 1;         // 0..1
    const int half = lane >> 4;
    const int r16  = lane & 15;

    const int nwg = gridDim.x, cpx = nwg >> 3;
    const int wg  = (blockIdx.x & 7) * cpx + (blockIdx.x >> 3);
    const int m0  = (wg / NBY) * BM;
    const int n0  = (wg % NBY) * BN;

    f32x4 acc[4][4] = {};

    auto stage = [&](int kt, int b) {   // 4 gl_lds per thread
        const int k0 = kt * BK;
        #pragma unroll
        for (int i = 0; i < 2; ++i) {       // A: 128 rows x 4 chunks = 512
            const int s   = i * 256 + tid;
            const int row = s >> 2, c = s & 3;
            const int csw = c ^ (row & 3);
            int gr = m0 + row; if (gr >= M) gr = M - 1;
            gl_lds16(&Ab[(size_t)gr * K + k0 + csw * 8], &sA[b][s * 8]);
        }
        #pragma unroll
        for (int i = 0; i < 2; ++i) {       // B: 128 rows x 4 chunks = 512
            const int s   = i * 256 + tid;
            const int row = s >> 2, c = s & 3;
            const int csw = c ^ (row & 3);
            gl_lds16(&Bb[(size_t)(n0 + row) * K + k0 + csw * 8], &sB[b][s * 8]);
        }
    };
    auto step = [&](int b) {
        bf16x8 bfr[4];
        #pragma unroll
        for (int n = 0; n < 4; ++n) {
            const int brow = wn * 64 + n * 16 + r16;
            bfr[n] = *(const bf16x8*)&sB[b][brow * 32 + (half ^ (brow & 3)) * 8];
        }
        #pragma unroll
        for (int m = 0; m < 4; ++m) {
            const int arow = wm * 64 + m * 16 + r16;
            const bf16x8 af = *(const bf16x8*)&sA[b][arow * 32 + (half ^ (arow & 3)) * 8];
            #pragma unroll
            for (int n = 0; n < 4; ++n)
                acc[m][n] = __builtin_amdgcn_mfma_f32_16x16x32_bf16(
                                af, bfr[n], acc[m][n], 0, 0, 0);
        }
    };

    stage(0, 0);
    stage(1, 1);
    for (int t = 0; t < nkt; ++t) {
        if (t + 1 < nkt) asm volatile("s_waitcnt vmcnt(4)" ::: "memory");
        else             asm volatile("s_waitcnt vmcnt(0)" ::: "memory");
        __builtin_amdgcn_s_barrier();
        __builtin_amdgcn_sched_barrier(0);
        step(t % 3);
        if (t + 2 < nkt) stage(t + 2, (t + 2) % 3);
    }

    #pragma unroll
    for (int m = 0; m < 4; ++m) {
        #pragma unroll
        for (int j = 0; j < 4; ++j) {
            const int gr = m0 + wm * 64 + m * 16 + half * 4 + j;
            if (gr >= M) continue;
            #pragma unroll
            for (int n = 0; n < 4; ++n) {
                const int gc = n0 + wn * 64 + n * 16 + r16;
                C[(size_t)gr * N + gc] = acc[m][n][j] + bias[gc];
            }
        }
    }
}

// ---------------------------------------------------------------------------
// CSR build: histogram -> 3-phase coalesced scan (seeds cursor) -> fill
// ---------------------------------------------------------------------------
__global__ __launch_bounds__(256) void row_histogram(
    const int* __restrict__ arow, int* __restrict__ cnt, int E)
{
    const int t = blockIdx.x * blockDim.x + threadIdx.x;
    const int n = gridDim.x * blockDim.x;
    for (int e = t; e < E; e += n)
        atomicAdd(&cnt[arow[e]], 1);
}

#define SCAN_NB 49      // 49 blocks x 256 thr x 4 elems = 50176 >= 50000

__global__ __launch_bounds__(256) void scan1(
    const int* __restrict__ cnt, int* __restrict__ bsum, int n)
{
    __shared__ int red[256];
    const int base = blockIdx.x * 1024 + threadIdx.x * 4;
    int s = 0;
    #pragma unroll
    for (int i = 0; i < 4; ++i) { const int idx = base + i; if (idx < n) s += cnt[idx]; }
    red[threadIdx.x] = s;
    __syncthreads();
    for (int off = 128; off > 0; off >>= 1) {
        if (threadIdx.x < off) red[threadIdx.x] += red[threadIdx.x + off];
        __syncthreads();
    }
    if (threadIdx.x == 0) bsum[blockIdx.x] = red[0];
}

__global__ __launch_bounds__(64) void scan2(int* __restrict__ bsum, int nb)
{
    if (threadIdx.x == 0) {
        int run = 0;
        for (int b = 0; b < nb; ++b) { const int v = bsum[b]; bsum[b] = run; run += v; }
        bsum[nb] = run;
    }
}

__global__ __launch_bounds__(256) void scan3(
    const int* __restrict__ cnt, const int* __restrict__ bsum,
    int* __restrict__ ptr, int* __restrict__ cursor, int n)
{
    __shared__ int hs[256];
    const int base = blockIdx.x * 1024 + threadIdx.x * 4;
    int loc[4]; int s = 0;
    #pragma unroll
    for (int i = 0; i < 4; ++i) {
        const int idx = base + i;
        loc[i] = (idx < n) ? cnt[idx] : 0;
        s += loc[i];
    }
    hs[threadIdx.x] = s;
    __syncthreads();
    for (int off = 1; off < 256; off <<= 1) {
        int v = (threadIdx.x >= off) ? hs[threadIdx.x - off] : 0;
        __syncthreads();
        hs[threadIdx.x] += v;
        __syncthreads();
    }
    int run = bsum[blockIdx.x] + ((threadIdx.x == 0) ? 0 : hs[threadIdx.x - 1]);
    #pragma unroll
    for (int i = 0; i < 4; ++i) {
        const int idx = base + i;
        if (idx < n) { ptr[idx] = run; cursor[idx] = run; }
        run += loc[i];
    }
    if (blockIdx.x == SCAN_NB - 1 && threadIdx.x == 255) ptr[n] = run;
}

__global__ __launch_bounds__(256) void csr_fill(
    const int*   __restrict__ arow,
    const int*   __restrict__ acol,
    const float* __restrict__ aval,
    int*         __restrict__ cursor,   // seeded with start offsets
    int2*        __restrict__ cpair,    // {col, val-bits}
    int E)
{
    const int t = blockIdx.x * blockDim.x + threadIdx.x;
    const int n = gridDim.x * blockDim.x;
    for (int e = t; e < E; e += n) {
        const int pos = atomicAdd(&cursor[arow[e]], 1);
        cpair[pos] = make_int2(acol[e], __float_as_int(aval[e]));
    }
}

// ---------------------------------------------------------------------------
// SpMM gather + relu: one wave per row; 2 edges in flight (32 lanes x 16B
// each); __shfl_xor(32) fold; lanes 0-31 store bf16x8.
// ---------------------------------------------------------------------------
__global__ __launch_bounds__(256) void spmm_gather(
    const int*    __restrict__ ptr,
    const int2*   __restrict__ cpair,
    const __bf16* __restrict__ support,
    __bf16*       __restrict__ agg,
    int n)
{
    const int tid  = threadIdx.x;
    const int lane = tid & 63;
    const int row  = blockIdx.x * 4 + (tid >> 6);
    if (row >= n) return;
    const int l32 = lane & 31, ep = lane >> 5;
    const int beg = ptr[row], end = ptr[row + 1];

    float a[8] = {0.f, 0.f, 0.f, 0.f, 0.f, 0.f, 0.f, 0.f};

    auto fma_edge = [&](const int2 p) {
        const float v = __int_as_float(p.y);
        const uint4 s = *(const uint4*)&support[(size_t)p.x * HID + l32 * 8];
        a[0] += v * __uint_as_float(s.x << 16);
        a[1] += v * __uint_as_float(s.x & 0xFFFF0000u);
        a[2] += v * __uint_as_float(s.y << 16);
        a[3] += v * __uint_as_float(s.y & 0xFFFF0000u);
        a[4] += v * __uint_as_float(s.z << 16);
        a[5] += v * __uint_as_float(s.z & 0xFFFF0000u);
        a[6] += v * __uint_as_float(s.w << 16);
        a[7] += v * __uint_as_float(s.w & 0xFFFF0000u);
    };

    int i = beg;
    for (; i + 4 <= end; i += 4) {          // 2 pairs in flight
        const int2 p0 = cpair[i + ep];
        const int2 p1 = cpair[i + 2 + ep];
        fma_edge(p0);
        fma_edge(p1);
    }
    if (i + 2 <= end) { fma_edge(cpair[i + ep]); i += 2; }
    if (i < end && ep == 0) fma_edge(cpair[i]);   // odd tail: low half only

    #pragma unroll
    for (int k = 0; k < 8; ++k) a[k] += __shfl_xor(a[k], 32);

    if (ep == 0) {
        bf16x8 o = { (__bf16)fmaxf(a[0], 0.f), (__bf16)fmaxf(a[1], 0.f),
                     (__bf16)fmaxf(a[2], 0.f), (__bf16)fmaxf(a[3], 0.f),
                     (__bf16)fmaxf(a[4], 0.f), (__bf16)fmaxf(a[5], 0.f),
                     (__bf16)fmaxf(a[6], 0.f), (__bf16)fmaxf(a[7], 0.f) };
        *(bf16x8*)&agg[(size_t)row * HID + l32 * 8] = o;
    }
}

extern "C" void kernel_launch(void* const* d_in, const int* in_sizes, int n_in,
                              void* d_out, int out_size, void* d_ws, size_t ws_size,
                              hipStream_t stream) {
    const float* context  = (const float*)d_in[0];
    const int*   adj_row  = (const int*)  d_in[1];
    const int*   adj_col  = (const int*)  d_in[2];
    const float* adj_val  = (const float*)d_in[3];
    const float* ctx_w    = (const float*)d_in[4];
    const float* out_w    = (const float*)d_in[5];
    const float* out_b    = (const float*)d_in[6];
    float*       out      = (float*)d_out;

    char* ws = (char*)d_ws;
    __bf16* support_b = (__bf16*)ws;  ws += (size_t)N_NODES * HID * 2;
    __bf16* agg_b     = (__bf16*)ws;  ws += (size_t)N_NODES * HID * 2;
    __bf16* ctxw_b    = (__bf16*)ws;  ws += (size_t)HID * VOCAB * 2;
    __bf16* outw_b    = (__bf16*)ws;  ws += (size_t)VOCAB * HID * 2;
    int*    csr_ptr   = (int*)ws;     ws += ((size_t)N_NODES + 16) * 4;
    int*    cnt       = (int*)ws;     ws += (size_t)N_NODES * 4;
    int*    cursor    = (int*)ws;     ws += (size_t)N_NODES * 4;
    int*    bsum      = (int*)ws;     ws += ((size_t)SCAN_NB + 16) * 4;
    int2*   cpair     = (int2*)ws;    ws += (size_t)N_EDGES * 8;

    // weight preconverts
    cvt_f32_bf16<<<(HID * VOCAB / 4 + 255) / 256, 256, 0, stream>>>(
        ctx_w, ctxw_b, HID * VOCAB / 4);
    cvt_f32_bf16<<<(VOCAB * HID / 4 + 255) / 256, 256, 0, stream>>>(
        out_w, outw_b, VOCAB * HID / 4);

    // GEMM1: support_b = bf16( context @ ctx_w^T )
    gemm1<<<dim3((N_NODES + 63) / 64), dim3(256), 0, stream>>>(
        context, ctxw_b, support_b, N_NODES);

    // CSR build
    hipMemsetAsync(cnt, 0, (size_t)N_NODES * 4, stream);
    row_histogram<<<1024, 256, 0, stream>>>(adj_row, cnt, N_EDGES);
    scan1<<<SCAN_NB, 256, 0, stream>>>(cnt, bsum, N_NODES);
    scan2<<<1, 64, 0, stream>>>(bsum, SCAN_NB);
    scan3<<<SCAN_NB, 256, 0, stream>>>(cnt, bsum, csr_ptr, cursor, N_NODES);
    csr_fill<<<1024, 256, 0, stream>>>(
        adj_row, adj_col, adj_val, cursor, cpair, N_EDGES);

    // SpMM gather + relu -> agg_b
    spmm_gather<<<(N_NODES + 3) / 4, 256, 0, stream>>>(
        csr_ptr, cpair, support_b, agg_b, N_NODES);

    // GEMM2: out = agg_b @ out_w^T + b
    gemm2<<<dim3(((N_NODES + 127) / 128) * (VOCAB / 128)), dim3(256), 0, stream>>>(
        agg_b, outw_b, out_b, out, N_NODES);
}

// Round 10
// 491.929 us; speedup vs baseline: 3.6320x; 1.3294x over previous
//
#include <hip/hip_runtime.h>
#include <hip/hip_bf16.h>

#define N_NODES 50000
#define VOCAB   2048
#define HID     256
#define N_EDGES 1600000

typedef __attribute__((ext_vector_type(8))) __bf16 bf16x8;
typedef __attribute__((ext_vector_type(4))) __bf16 bf16x4;
typedef __attribute__((ext_vector_type(4))) float  f32x4;

// async global->LDS, 16B per lane (HW: lds dst = wave-uniform base + lane*16)
__device__ __forceinline__ void gl_lds16(const void* g, void* l) {
    __builtin_amdgcn_global_load_lds(
        (const __attribute__((address_space(1))) void*)g,
        (__attribute__((address_space(3))) void*)l, 16, 0, 0);
}

// ---------------------------------------------------------------------------
// Launch 1: {zero cnt} || {cvt ctx_w -> bf16}.  561 blocks.
// ---------------------------------------------------------------------------
#define ZERO_NB 49
__global__ __launch_bounds__(256) void phase1(
    const float* __restrict__ w, __bf16* __restrict__ wb, int n4,
    int* __restrict__ cnt, int ncnt)
{
    int bid = blockIdx.x;
    if (bid < ZERO_NB) {
        const int base = bid * 1024 + threadIdx.x * 4;
        if (base + 3 < ncnt)      *(int4*)&cnt[base] = make_int4(0, 0, 0, 0);
        else                      for (int i = 0; i < 4; ++i)
                                      if (base + i < ncnt) cnt[base + i] = 0;
        return;
    }
    const int t = (bid - ZERO_NB) * 256 + threadIdx.x;
    if (t < n4) {
        const float4 v = ((const float4*)w)[t];
        bf16x4 p = { (__bf16)v.x, (__bf16)v.y, (__bf16)v.z, (__bf16)v.w };
        ((bf16x4*)wb)[t] = p;
    }
}

// ---------------------------------------------------------------------------
// Launch 2: {hist} || {cvt out_w} || {gemm1}.  96 + 64 + 782 = 942 blocks.
// hist/cvt are independent of gemm1 and run concurrently on spare CUs.
// gemm1: support_b[M][256] = bf16( A_f32[M][2048] @ Bb[256][2048]^T )
//   BM=64,BN=256,BK=32, 4 waves (1x4, 64x64), triple-buffered gl_lds,
//   counted vmcnt(6) + raw s_barrier (T4). XOR source-swizzle (rule 21).
// ---------------------------------------------------------------------------
#define HIST_NB 96
#define CVTW_NB 64
__global__ __launch_bounds__(256) void phase2(
    const float*  __restrict__ Af,     // [M][2048] fp32 (context)
    const __bf16* __restrict__ Bb,     // [256][2048] bf16 (ctxw_b)
    __bf16*       __restrict__ Cb,     // [M][256] bf16 (support_b)
    int M,
    const int*    __restrict__ arow, int* __restrict__ cnt, int E,
    const float*  __restrict__ w2,   __bf16* __restrict__ w2b, int n4w)
{
    const int tid = threadIdx.x;
    int bid = blockIdx.x;

    if (bid < HIST_NB) {                    // ---- histogram (int4 reads) ----
        const int stride = HIST_NB * 256;
        for (int e4 = bid * 256 + tid; e4 < E / 4; e4 += stride) {
            const int4 r = ((const int4*)arow)[e4];
            atomicAdd(&cnt[r.x], 1); atomicAdd(&cnt[r.y], 1);
            atomicAdd(&cnt[r.z], 1); atomicAdd(&cnt[r.w], 1);
        }
        return;
    }
    bid -= HIST_NB;
    if (bid < CVTW_NB) {                    // ---- cvt out_w -> bf16 ----
        const int stride = CVTW_NB * 256;
        for (int t = bid * 256 + tid; t < n4w; t += stride) {
            const float4 v = ((const float4*)w2)[t];
            bf16x4 p = { (__bf16)v.x, (__bf16)v.y, (__bf16)v.z, (__bf16)v.w };
            ((bf16x4*)w2b)[t] = p;
        }
        return;
    }
    bid -= CVTW_NB;                         // ---- gemm1 ----

    constexpr int K = 2048, N = 256, BM = 64, BK = 32, nkt = K / BK;
    __shared__ float  sAf[3][BM * BK];     // 3 x  8 KB
    __shared__ __bf16 sB [3][N  * BK];     // 3 x 16 KB  (72 KB total)

    const int lane = tid & 63;
    const int wn   = tid >> 6;        // 0..3 (col-wave)
    const int half = lane >> 4;       // 0..3
    const int r16  = lane & 15;
    const int m0   = bid * BM;

    f32x4 acc[4][4] = {};

    auto stage = [&](int kt, int b) {   // 6 gl_lds per thread
        const int k0 = kt * BK;
        #pragma unroll
        for (int i = 0; i < 2; ++i) {   // A: 64 rows x 8 chunks(16B)
            const int s   = i * 256 + tid;
            const int row = s >> 3, c = s & 7;
            const int csw = c ^ (row & 7);
            int gr = m0 + row; if (gr >= M) gr = M - 1;
            gl_lds16(&Af[(size_t)gr * K + k0 + csw * 4], &sAf[b][s * 4]);
        }
        #pragma unroll
        for (int i = 0; i < 4; ++i) {   // B: 256 rows x 4 chunks(16B)
            const int s   = i * 256 + tid;
            const int row = s >> 2, c = s & 3;
            const int csw = c ^ (row & 3);
            gl_lds16(&Bb[(size_t)row * K + k0 + csw * 8], &sB[b][s * 8]);
        }
    };
    auto step = [&](int b) {
        bf16x8 bfr[4];
        #pragma unroll
        for (int n = 0; n < 4; ++n) {
            const int brow = wn * 64 + n * 16 + r16;
            bfr[n] = *(const bf16x8*)&sB[b][brow * 32 + (half ^ (brow & 3)) * 8];
        }
        #pragma unroll
        for (int m = 0; m < 4; ++m) {
            const int arw = m * 16 + r16;
            const int rx  = arw & 7;
            const f32x4 lo = *(const f32x4*)&sAf[b][arw * 32 + ((2 * half)     ^ rx) * 4];
            const f32x4 hi = *(const f32x4*)&sAf[b][arw * 32 + ((2 * half + 1) ^ rx) * 4];
            const bf16x8 af = { (__bf16)lo.x, (__bf16)lo.y, (__bf16)lo.z, (__bf16)lo.w,
                                (__bf16)hi.x, (__bf16)hi.y, (__bf16)hi.z, (__bf16)hi.w };
            #pragma unroll
            for (int n = 0; n < 4; ++n)
                acc[m][n] = __builtin_amdgcn_mfma_f32_16x16x32_bf16(
                                af, bfr[n], acc[m][n], 0, 0, 0);
        }
    };

    stage(0, 0);
    stage(1, 1);
    for (int t = 0; t < nkt; ++t) {
        if (t + 1 < nkt) asm volatile("s_waitcnt vmcnt(6)" ::: "memory");
        else             asm volatile("s_waitcnt vmcnt(0)" ::: "memory");
        __builtin_amdgcn_s_barrier();
        __builtin_amdgcn_sched_barrier(0);
        step(t % 3);
        if (t + 2 < nkt) stage(t + 2, (t + 2) % 3);
    }

    // epilogue: C/D layout col=lane&15, row=(lane>>4)*4+j (m89-verified)
    #pragma unroll
    for (int m = 0; m < 4; ++m) {
        #pragma unroll
        for (int j = 0; j < 4; ++j) {
            const int gr = m0 + m * 16 + half * 4 + j;
            if (gr >= M) continue;
            #pragma unroll
            for (int n = 0; n < 4; ++n) {
                const int gc = wn * 64 + n * 16 + r16;
                Cb[(size_t)gr * N + gc] = (__bf16)acc[m][n][j];
            }
        }
    }
}

// ---------------------------------------------------------------------------
// 3-phase coalesced scan (seeds cursor)
// ---------------------------------------------------------------------------
#define SCAN_NB 49      // 49 x 256 x 4 = 50176 >= 50000

__global__ __launch_bounds__(256) void scan1(
    const int* __restrict__ cnt, int* __restrict__ bsum, int n)
{
    __shared__ int red[256];
    const int base = blockIdx.x * 1024 + threadIdx.x * 4;
    int s = 0;
    #pragma unroll
    for (int i = 0; i < 4; ++i) { const int idx = base + i; if (idx < n) s += cnt[idx]; }
    red[threadIdx.x] = s;
    __syncthreads();
    for (int off = 128; off > 0; off >>= 1) {
        if (threadIdx.x < off) red[threadIdx.x] += red[threadIdx.x + off];
        __syncthreads();
    }
    if (threadIdx.x == 0) bsum[blockIdx.x] = red[0];
}

__global__ __launch_bounds__(64) void scan2(int* __restrict__ bsum, int nb)
{
    if (threadIdx.x == 0) {
        int run = 0;
        for (int b = 0; b < nb; ++b) { const int v = bsum[b]; bsum[b] = run; run += v; }
        bsum[nb] = run;
    }
}

__global__ __launch_bounds__(256) void scan3(
    const int* __restrict__ cnt, const int* __restrict__ bsum,
    int* __restrict__ ptr, int* __restrict__ cursor, int n)
{
    __shared__ int hs[256];
    const int base = blockIdx.x * 1024 + threadIdx.x * 4;
    int loc[4]; int s = 0;
    #pragma unroll
    for (int i = 0; i < 4; ++i) {
        const int idx = base + i;
        loc[i] = (idx < n) ? cnt[idx] : 0;
        s += loc[i];
    }
    hs[threadIdx.x] = s;
    __syncthreads();
    for (int off = 1; off < 256; off <<= 1) {
        int v = (threadIdx.x >= off) ? hs[threadIdx.x - off] : 0;
        __syncthreads();
        hs[threadIdx.x] += v;
        __syncthreads();
    }
    int run = bsum[blockIdx.x] + ((threadIdx.x == 0) ? 0 : hs[threadIdx.x - 1]);
    #pragma unroll
    for (int i = 0; i < 4; ++i) {
        const int idx = base + i;
        if (idx < n) { ptr[idx] = run; cursor[idx] = run; }
        run += loc[i];
    }
    if (blockIdx.x == SCAN_NB - 1 && threadIdx.x == 255) ptr[n] = run;
}

// ---------------------------------------------------------------------------
// csr_fill: 4 edges per thread (int4/float4 reads), scattered int2 writes
// ---------------------------------------------------------------------------
__global__ __launch_bounds__(256) void csr_fill(
    const int*   __restrict__ arow,
    const int*   __restrict__ acol,
    const float* __restrict__ aval,
    int*         __restrict__ cursor,   // seeded with start offsets
    int2*        __restrict__ cpair,    // {col, val-bits}
    int E)
{
    const int stride = gridDim.x * blockDim.x;
    for (int e4 = blockIdx.x * blockDim.x + threadIdx.x; e4 < E / 4; e4 += stride) {
        const int4   r = ((const int4*)arow)[e4];
        const int4   c = ((const int4*)acol)[e4];
        const float4 v = ((const float4*)aval)[e4];
        int p;
        p = atomicAdd(&cursor[r.x], 1); cpair[p] = make_int2(c.x, __float_as_int(v.x));
        p = atomicAdd(&cursor[r.y], 1); cpair[p] = make_int2(c.y, __float_as_int(v.y));
        p = atomicAdd(&cursor[r.z], 1); cpair[p] = make_int2(c.z, __float_as_int(v.z));
        p = atomicAdd(&cursor[r.w], 1); cpair[p] = make_int2(c.w, __float_as_int(v.w));
    }
}

// ---------------------------------------------------------------------------
// SpMM gather + relu: one wave per row; 4 gathers in flight (32 lanes x 16B
// each, 2 edge-groups); __shfl_xor(32) fold; lanes 0-31 store bf16x8.
// ---------------------------------------------------------------------------
__global__ __launch_bounds__(256) void spmm_gather(
    const int*    __restrict__ ptr,
    const int2*   __restrict__ cpair,
    const __bf16* __restrict__ support,
    __bf16*       __restrict__ agg,
    int n)
{
    const int tid  = threadIdx.x;
    const int lane = tid & 63;
    const int row  = blockIdx.x * 4 + (tid >> 6);
    if (row >= n) return;
    const int l32 = lane & 31, ep = lane >> 5;
    const int beg = ptr[row], end = ptr[row + 1];

    float a[8] = {0.f, 0.f, 0.f, 0.f, 0.f, 0.f, 0.f, 0.f};

    auto fma8 = [&](float v, const uint4& s) {
        a[0] += v * __uint_as_float(s.x << 16);
        a[1] += v * __uint_as_float(s.x & 0xFFFF0000u);
        a[2] += v * __uint_as_float(s.y << 16);
        a[3] += v * __uint_as_float(s.y & 0xFFFF0000u);
        a[4] += v * __uint_as_float(s.z << 16);
        a[5] += v * __uint_as_float(s.z & 0xFFFF0000u);
        a[6] += v * __uint_as_float(s.w << 16);
        a[7] += v * __uint_as_float(s.w & 0xFFFF0000u);
    };

    int i = beg;
    for (; i + 8 <= end; i += 8) {      // 4 gathers in flight per lane
        const int2 p0 = cpair[i + ep];
        const int2 p1 = cpair[i + 2 + ep];
        const int2 p2 = cpair[i + 4 + ep];
        const int2 p3 = cpair[i + 6 + ep];
        const uint4 s0 = *(const uint4*)&support[(size_t)p0.x * HID + l32 * 8];
        const uint4 s1 = *(const uint4*)&support[(size_t)p1.x * HID + l32 * 8];
        const uint4 s2 = *(const uint4*)&support[(size_t)p2.x * HID + l32 * 8];
        const uint4 s3 = *(const uint4*)&support[(size_t)p3.x * HID + l32 * 8];
        fma8(__int_as_float(p0.y), s0);
        fma8(__int_as_float(p1.y), s1);
        fma8(__int_as_float(p2.y), s2);
        fma8(__int_as_float(p3.y), s3);
    }
    for (; i + 2 <= end; i += 2) {
        const int2 p = cpair[i + ep];
        const uint4 s = *(const uint4*)&support[(size_t)p.x * HID + l32 * 8];
        fma8(__int_as_float(p.y), s);
    }
    if (i < end && ep == 0) {
        const int2 p = cpair[i];
        const uint4 s = *(const uint4*)&support[(size_t)p.x * HID + l32 * 8];
        fma8(__int_as_float(p.y), s);
    }

    #pragma unroll
    for (int k = 0; k < 8; ++k) a[k] += __shfl_xor(a[k], 32);

    if (ep == 0) {
        bf16x8 o = { (__bf16)fmaxf(a[0], 0.f), (__bf16)fmaxf(a[1], 0.f),
                     (__bf16)fmaxf(a[2], 0.f), (__bf16)fmaxf(a[3], 0.f),
                     (__bf16)fmaxf(a[4], 0.f), (__bf16)fmaxf(a[5], 0.f),
                     (__bf16)fmaxf(a[6], 0.f), (__bf16)fmaxf(a[7], 0.f) };
        *(bf16x8*)&agg[(size_t)row * HID + l32 * 8] = o;
    }
}

// ---------------------------------------------------------------------------
// GEMM2: out[M][2048] = Ab[M][256] @ Bb[2048][256]^T + bias
// BM=128,BN=128,BK=32, 4 waves (2x2), triple-buffered gl_lds, vmcnt(4),
// XCD-chunked swizzle, NONTEMPORAL C stores (410 MB never re-read).
// ---------------------------------------------------------------------------
__global__ __launch_bounds__(256) void gemm2(
    const __bf16* __restrict__ Ab,    // [M][256] bf16
    const __bf16* __restrict__ Bb,    // [2048][256] bf16
    const float*  __restrict__ bias,  // [2048]
    float*        __restrict__ C,     // [M][2048] fp32
    int M)
{
    constexpr int K = 256, N = 2048, BM = 128, BN = 128, BK = 32;
    constexpr int NBY = N / BN, nkt = K / BK;
    __shared__ __bf16 sA[3][BM * BK];   // 3 x 8 KB
    __shared__ __bf16 sB[3][BN * BK];   // 3 x 8 KB  (48 KB total)

    const int tid  = threadIdx.x;
    const int lane = tid & 63;
    const int wid  = tid >> 6;
    const int wm   = wid >> 1;
    const int wn   = wid & 1;
    const int half = lane >> 4;
    const int r16  = lane & 15;

    const int nwg = gridDim.x, cpx = nwg >> 3;
    const int wg  = (blockIdx.x & 7) * cpx + (blockIdx.x >> 3);
    const int m0  = (wg / NBY) * BM;
    const int n0  = (wg % NBY) * BN;

    f32x4 acc[4][4] = {};

    auto stage = [&](int kt, int b) {   // 4 gl_lds per thread
        const int k0 = kt * BK;
        #pragma unroll
        for (int i = 0; i < 2; ++i) {
            const int s   = i * 256 + tid;
            const int row = s >> 2, c = s & 3;
            const int csw = c ^ (row & 3);
            int gr = m0 + row; if (gr >= M) gr = M - 1;
            gl_lds16(&Ab[(size_t)gr * K + k0 + csw * 8], &sA[b][s * 8]);
        }
        #pragma unroll
        for (int i = 0; i < 2; ++i) {
            const int s   = i * 256 + tid;
            const int row = s >> 2, c = s & 3;
            const int csw = c ^ (row & 3);
            gl_lds16(&Bb[(size_t)(n0 + row) * K + k0 + csw * 8], &sB[b][s * 8]);
        }
    };
    auto step = [&](int b) {
        bf16x8 bfr[4];
        #pragma unroll
        for (int n = 0; n < 4; ++n) {
            const int brow = wn * 64 + n * 16 + r16;
            bfr[n] = *(const bf16x8*)&sB[b][brow * 32 + (half ^ (brow & 3)) * 8];
        }
        #pragma unroll
        for (int m = 0; m < 4; ++m) {
            const int arw = wm * 64 + m * 16 + r16;
            const bf16x8 af = *(const bf16x8*)&sA[b][arw * 32 + (half ^ (arw & 3)) * 8];
            #pragma unroll
            for (int n = 0; n < 4; ++n)
                acc[m][n] = __builtin_amdgcn_mfma_f32_16x16x32_bf16(
                                af, bfr[n], acc[m][n], 0, 0, 0);
        }
    };

    stage(0, 0);
    stage(1, 1);
    for (int t = 0; t < nkt; ++t) {
        if (t + 1 < nkt) asm volatile("s_waitcnt vmcnt(4)" ::: "memory");
        else             asm volatile("s_waitcnt vmcnt(0)" ::: "memory");
        __builtin_amdgcn_s_barrier();
        __builtin_amdgcn_sched_barrier(0);
        step(t % 3);
        if (t + 2 < nkt) stage(t + 2, (t + 2) % 3);
    }

    #pragma unroll
    for (int m = 0; m < 4; ++m) {
        #pragma unroll
        for (int j = 0; j < 4; ++j) {
            const int gr = m0 + wm * 64 + m * 16 + half * 4 + j;
            if (gr >= M) continue;
            #pragma unroll
            for (int n = 0; n < 4; ++n) {
                const int gc = n0 + wn * 64 + n * 16 + r16;
                __builtin_nontemporal_store(acc[m][n][j] + bias[gc],
                                            &C[(size_t)gr * N + gc]);
            }
        }
    }
}

extern "C" void kernel_launch(void* const* d_in, const int* in_sizes, int n_in,
                              void* d_out, int out_size, void* d_ws, size_t ws_size,
                              hipStream_t stream) {
    const float* context  = (const float*)d_in[0];
    const int*   adj_row  = (const int*)  d_in[1];
    const int*   adj_col  = (const int*)  d_in[2];
    const float* adj_val  = (const float*)d_in[3];
    const float* ctx_w    = (const float*)d_in[4];
    const float* out_w    = (const float*)d_in[5];
    const float* out_b    = (const float*)d_in[6];
    float*       out      = (float*)d_out;

    char* ws = (char*)d_ws;
    __bf16* support_b = (__bf16*)ws;  ws += (size_t)N_NODES * HID * 2;
    __bf16* agg_b     = (__bf16*)ws;  ws += (size_t)N_NODES * HID * 2;
    __bf16* ctxw_b    = (__bf16*)ws;  ws += (size_t)HID * VOCAB * 2;
    __bf16* outw_b    = (__bf16*)ws;  ws += (size_t)VOCAB * HID * 2;
    int*    csr_ptr   = (int*)ws;     ws += ((size_t)N_NODES + 16) * 4;
    int*    cnt       = (int*)ws;     ws += (size_t)N_NODES * 4;
    int*    cursor    = (int*)ws;     ws += (size_t)N_NODES * 4;
    int*    bsum      = (int*)ws;     ws += ((size_t)SCAN_NB + 16) * 4;
    int2*   cpair     = (int2*)ws;    ws += (size_t)N_EDGES * 8;

    constexpr int N4 = HID * VOCAB / 4;      // 131072 float4 per weight

    // L1: zero cnt || cvt ctx_w
    phase1<<<dim3(ZERO_NB + (N4 + 255) / 256), 256, 0, stream>>>(
        ctx_w, ctxw_b, N4, cnt, N_NODES);

    // L2: hist || cvt out_w || gemm1
    phase2<<<dim3(HIST_NB + CVTW_NB + (N_NODES + 63) / 64), 256, 0, stream>>>(
        context, ctxw_b, support_b, N_NODES,
        adj_row, cnt, N_EDGES,
        out_w, outw_b, N4);

    // L3-5: scan (ptr + cursor seed)
    scan1<<<SCAN_NB, 256, 0, stream>>>(cnt, bsum, N_NODES);
    scan2<<<1, 64, 0, stream>>>(bsum, SCAN_NB);
    scan3<<<SCAN_NB, 256, 0, stream>>>(cnt, bsum, csr_ptr, cursor, N_NODES);

    // L6: CSR fill
    csr_fill<<<512, 256, 0, stream>>>(
        adj_row, adj_col, adj_val, cursor, cpair, N_EDGES);

    // L7: SpMM gather + relu
    spmm_gather<<<(N_NODES + 3) / 4, 256, 0, stream>>>(
        csr_ptr, cpair, support_b, agg_b, N_NODES);

    // L8: GEMM2
    gemm2<<<dim3(((N_NODES + 127) / 128) * (VOCAB / 128)), 256, 0, stream>>>(
        agg_b, outw_b, out_b, out, N_NODES);
}